// Round 12
// baseline (272.048 us; speedup 1.0000x reference)
//
#include <hip/hip_runtime.h>
#include <hip/hip_bf16.h>
#include <stdint.h>

#define M_DIM 4096
#define N_DIM 11008
#define K_DIM 4096
#define KP    (K_DIM / 2)   // packed int32s per weight row

typedef __attribute__((ext_vector_type(4))) int i32x4;

#define AS1 __attribute__((address_space(1)))
#define AS3 __attribute__((address_space(3)))

// ---------------- Fused pre-pass: quant_x (blocks 0..4095) + pack_q (blocks 4096..6143) ----------------
__global__ __launch_bounds__(256) void prep(const float* __restrict__ x,
                                            const int* __restrict__ pw,
                                            signed char* __restrict__ xq,
                                            signed char* __restrict__ wq,
                                            float* __restrict__ r,
                                            float* __restrict__ sx) {
  const int b = blockIdx.x;
  const int t = threadIdx.x;
  if (b < 4096) {
    // --- per-row quantize x -> i8, emit r[b]=sum(x), sx[b]=scale ---
    const int row = b;
    const int lane = t & 63, wid = t >> 6;
    const float4* x4 = (const float4*)(x + (size_t)row * K_DIM);
    float4 v[4];
    float am = 0.0f, sm = 0.0f;
#pragma unroll
    for (int i = 0; i < 4; ++i) {
      v[i] = x4[i * 256 + t];
      sm += v[i].x + v[i].y + v[i].z + v[i].w;
      am = fmaxf(am, fmaxf(fmaxf(fabsf(v[i].x), fabsf(v[i].y)),
                           fmaxf(fabsf(v[i].z), fabsf(v[i].w))));
    }
#pragma unroll
    for (int off = 32; off >= 1; off >>= 1) {
      am = fmaxf(am, __shfl_xor(am, off));
      sm += __shfl_xor(sm, off);
    }
    __shared__ float smax[4], ssum[4];
    if (lane == 0) { smax[wid] = am; ssum[wid] = sm; }
    __syncthreads();
    am = fmaxf(fmaxf(smax[0], smax[1]), fmaxf(smax[2], smax[3]));
    sm = ssum[0] + ssum[1] + ssum[2] + ssum[3];
    const float inv = am > 0.0f ? 127.0f / am : 0.0f;
    unsigned int* xo = (unsigned int*)(xq + (size_t)row * K_DIM);
#pragma unroll
    for (int i = 0; i < 4; ++i) {
      int q0 = min(127, max(-127, __float2int_rn(v[i].x * inv)));
      int q1 = min(127, max(-127, __float2int_rn(v[i].y * inv)));
      int q2 = min(127, max(-127, __float2int_rn(v[i].z * inv)));
      int q3 = min(127, max(-127, __float2int_rn(v[i].w * inv)));
      xo[i * 256 + t] = ((unsigned int)q0 & 0xFF) | (((unsigned int)q1 & 0xFF) << 8) |
                        (((unsigned int)q2 & 0xFF) << 16) | (((unsigned int)q3 & 0xFF) << 24);
    }
    if (t == 0) { r[row] = sm; sx[row] = am > 0.0f ? am / 127.0f : 0.0f; }
  } else {
    // --- repack nibbles -> q' = 2q-15 as i8 [N][K] ---
    const int total = (N_DIM * KP) / 4;  // int4 items; 4 int32 -> 8 i8
    for (int i = (b - 4096) * 256 + t; i < total; i += 2048 * 256) {
      int4 p = ((const int4*)pw)[i];
      int v[4] = {p.x, p.y, p.z, p.w};
      unsigned int u0 = 0, u1 = 0;
#pragma unroll
      for (int j = 0; j < 2; ++j) {
        unsigned int b0 = (unsigned int)(2 * (v[j] & 15) - 15) & 0xFF;
        unsigned int b1 = (unsigned int)(2 * ((v[j] >> 4) & 15) - 15) & 0xFF;
        u0 |= (b0 | (b1 << 8)) << (16 * j);
      }
#pragma unroll
      for (int j = 0; j < 2; ++j) {
        unsigned int b0 = (unsigned int)(2 * (v[2 + j] & 15) - 15) & 0xFF;
        unsigned int b1 = (unsigned int)(2 * ((v[2 + j] >> 4) & 15) - 15) & 0xFF;
        u1 |= (b0 | (b1 << 8)) << (16 * j);
      }
      uint2 st; st.x = u0; st.y = u1;
      ((uint2*)wq)[i] = st;
    }
  }
}

// ---------------- Main: 256x256 tile, BK=128 (i8), 16-wave pipelined i8 MFMA GEMM ----------------
// G'[M,N] = Xq[M,K] @ Wq[N,K]^T in i32; epilogue: out = s[o]*(0.5*sx[b]*G' + (7.5-zp[o])*r[b]).
// R12 change: 16 WAVES (1024 threads), wave-tile 64x64 (4M x 4N), acc 64 regs/wave.
// R11 diagnosis: 2 waves/SIMD barrier-locked -> LDS reads and MFMA serialized (K-tile
// 4730 cyc vs both-pipe floors ~2800/2613). With acc=64 + i8 frags, total regs/wave
// ~125 fits the 4-waves/SIMD budget (launch_bounds(1024,4)) -> 4-way wave interleave
// per SIMD covers phase-start lgkm latency and mixes read/MFMA issue. Cost accepted:
// LDS reads 192->256 KB/K-tile (4x4 wave grid). Everything proven stays frozen:
// 128B-row XOR-swizzled LDS (0 conflicts R7-R11), linear GLL dst (m104), 2 fences
// per K-tile, counted vmcnt (now WAITV(2): 1 GLL per half-slot per thread), no setprio.
#define BM 256
#define BN 256
#define BK 128                  // i8 elements per K-tile
#define NTILE (K_DIM / BK)      // 32
#define NT_M (M_DIM / BM)       // 16
#define NT_N (N_DIM / BN)       // 43
#define NWG  (NT_M * NT_N)      // 688 (div by 8 -> XCD swizzle bijective)
#define HS 16384                // half-slot bytes
#define PS 65536                // parity stride (4 half-slots)

#define WAITV(n) asm volatile("s_waitcnt vmcnt(" #n ")" ::: "memory")
#define WAITL0   asm volatile("s_waitcnt lgkmcnt(0)" ::: "memory")
#define BARR     do { asm volatile("" ::: "memory"); __builtin_amdgcn_s_barrier(); asm volatile("" ::: "memory"); } while (0)
#define SCHED0   __builtin_amdgcn_sched_barrier(0)

__global__ __launch_bounds__(1024, 4) void gemm_i8(const signed char* __restrict__ Xq,
                                                   const signed char* __restrict__ Wq,
                                                   const float* __restrict__ sc,
                                                   const float* __restrict__ zp,
                                                   const float* __restrict__ rbuf,
                                                   const float* __restrict__ sxbuf,
                                                   float* __restrict__ C) {
  __shared__ __align__(16) unsigned char lds8[131072];  // 128 KiB

  const int t = threadIdx.x;
  const int bid = blockIdx.x;
  const int swz = (bid & 7) * (NWG / 8) + (bid >> 3);  // T1 XCD swizzle
  const int tm = swz & 15;   // M-tile
  const int tn = swz >> 4;   // N-tile

  // --- stage sources: 1024 threads, thread t owns LDS chunk c=t of each 16KB half-slot.
  // chunk c: row = c>>3 (0..127), slot j = c&7, global chunk g = j ^ (row&7); 16 B/chunk.
  const int srow = t >> 3;
  const int g0 = (t & 7) ^ (srow & 7);
  const int koff = g0 * 16;                      // BYTE offset within K-tile
  const signed char* pB0 = Wq + (size_t)(tn * BN + srow) * K_DIM + koff;        // B rows 0-127
  const signed char* pB1 = Wq + (size_t)(tn * BN + 128 + srow) * K_DIM + koff;  // B rows 128-255
  const signed char* pA0 = Xq + (size_t)(tm * BM + srow) * K_DIM + koff;        // A rows 0-127
  const signed char* pA1 = Xq + (size_t)(tm * BM + 128 + srow) * K_DIM + koff;  // A rows 128-255
  const int d = t * 16;            // linear LDS byte offset within a half-slot (m104 rule)

  // --- wave / lane geometry: 16 waves = 4M x 4N; wave-tile 64x64
  const int lane = t & 63;
  const int w = t >> 6;
  const int wm = w >> 2;          // 0..3: rows wm*64..+63 (A-half = wm>>1)
  const int wn = w & 3;           // 0..3: cols wn*64..+63 (B-half = wn>>1)
  const int lr = lane & 15, lk = lane >> 4;

  // fragment read bases (BYTES). row stride 128 B; frag (row, chunk g=ks*4+lk) at
  // slot j = g ^ (lr&7); ks=1 flips chunk bit2 -> addr ^ 64. frag i/n: +2048 each.
  const int j0 = lk ^ (lr & 7);
  const int aB0 = (2 + (wm >> 1)) * HS + ((wm & 1) * 64 + lr) * 128 + j0 * 16;
  const int bB0 = (wn >> 1) * HS + ((wn & 1) * 64 + lr) * 128 + j0 * 16;

  i32x4 acc[4][4] = {};

#define GLL(src, dstoff) \
  __builtin_amdgcn_global_load_lds((const AS1 void*)(src), (AS3 void*)(lds8 + (dstoff)), 16, 0, 0)

  // ---- prologue: stage B0,B1,A0,A1 of tile0 (parity0), B0,B1 of tile1 (parity1)
  GLL(pB0, 0 * HS + d);
  GLL(pB1, 1 * HS + d);
  GLL(pA0, 2 * HS + d);
  GLL(pA1, 3 * HS + d);
  GLL(pB0 + BK, 4 * HS + d);
  GLL(pB1 + BK, 5 * HS + d);
  pB0 += 2 * BK; pB1 += 2 * BK;   // next B stage: tile 2
  pA0 += BK;     pA1 += BK;       // next A stage: tile 1
  WAITV(2);  // retire tile0's 4 halves; B(tile1) 2 stay in flight
  BARR;

  // VMODE: 0 -> WAITV(2), 1 -> WAITV(0), 2 -> none
#define TILE(P, SA, SB, VMODE) do {                                                        \
    i32x4 a0[4], b0[4], a1[4], b1[4];                                                      \
    /* ---- P1: reads kk0 (8); stage A0(t+1); MFMA 16 (kk0) ---- */                        \
    _Pragma("unroll") for (int i = 0; i < 4; ++i)                                          \
      a0[i] = *(const i32x4*)(lds8 + (P) * PS + aB0 + i * 2048);                           \
    _Pragma("unroll") for (int n = 0; n < 4; ++n)                                          \
      b0[n] = *(const i32x4*)(lds8 + (P) * PS + bB0 + n * 2048);                           \
    if (SA) { GLL(pA0, (((P) ^ 1) * 4 + 2) * HS + d); pA0 += BK; }                         \
    SCHED0;                                                                                \
    _Pragma("unroll") for (int i = 0; i < 4; ++i)                                          \
      _Pragma("unroll") for (int n = 0; n < 4; ++n)                                        \
        acc[i][n] = __builtin_amdgcn_mfma_i32_16x16x64_i8(a0[i], b0[n], acc[i][n], 0, 0, 0); \
    /* ---- P2: reads kk1 (8); stage A1(t+1); MFMA 8 (kk1, n=0,1); lgkm0; MID BARR ---- */ \
    _Pragma("unroll") for (int i = 0; i < 4; ++i)                                          \
      a1[i] = *(const i32x4*)(lds8 + (P) * PS + (aB0 ^ 64) + i * 2048);                    \
    _Pragma("unroll") for (int n = 0; n < 4; ++n)                                          \
      b1[n] = *(const i32x4*)(lds8 + (P) * PS + (bB0 ^ 64) + n * 2048);                    \
    if (SA) { GLL(pA1, (((P) ^ 1) * 4 + 3) * HS + d); pA1 += BK; }                         \
    SCHED0;                                                                                \
    _Pragma("unroll") for (int i = 0; i < 4; ++i)                                          \
      _Pragma("unroll") for (int n = 0; n < 2; ++n)                                        \
        acc[i][n] = __builtin_amdgcn_mfma_i32_16x16x64_i8(a1[i], b1[n], acc[i][n], 0, 0, 0); \
    WAITL0;                                                                                \
    BARR;                                                                                  \
    /* ---- P3: stage B0,B1(t+2); MFMA 8 (kk1, n=2,3); WAITV; END BARR ---- */             \
    if (SB) { GLL(pB0, ((P) * 4 + 0) * HS + d); pB0 += BK;                                 \
              GLL(pB1, ((P) * 4 + 1) * HS + d); pB1 += BK; }                               \
    SCHED0;                                                                                \
    _Pragma("unroll") for (int i = 0; i < 4; ++i)                                          \
      _Pragma("unroll") for (int n = 2; n < 4; ++n)                                        \
        acc[i][n] = __builtin_amdgcn_mfma_i32_16x16x64_i8(a1[i], b1[n], acc[i][n], 0, 0, 0); \
    if ((VMODE) == 0) { WAITV(2); } else if ((VMODE) == 1) { WAITV(0); }                   \
    BARR;                                                                                  \
  } while (0)

  // main loop: tiles 0..29
  for (int it = 0; it < (NTILE - 2) / 2; ++it) {
    TILE(0, 1, 1, 0);
    TILE(1, 1, 1, 0);
  }
  TILE(0, 1, 0, 1);   // tile 30: stage A(31) only; drain all (B(31)+A(31))
  TILE(1, 0, 0, 2);   // tile 31: no stage, no wait

#undef TILE
#undef GLL

  // epilogue: C/D layout col=lane&15, row=(lane>>4)*4+reg (dtype-independent, validated)
  const int row0 = tm * BM + wm * 64 + lk * 4;
  const int col0 = tn * BN + wn * 64 + lr;
  float sv[4], zv[4];
#pragma unroll
  for (int n = 0; n < 4; ++n) {
    sv[n] = sc[col0 + n * 16];
    zv[n] = 7.5f - zp[col0 + n * 16];
  }
#pragma unroll
  for (int i = 0; i < 4; ++i)
#pragma unroll
    for (int rr = 0; rr < 4; ++rr) {
      const int row = row0 + i * 16 + rr;
      const float rv = rbuf[row];
      const float hx = 0.5f * sxbuf[row];
#pragma unroll
      for (int n = 0; n < 4; ++n)
        C[(size_t)row * N_DIM + col0 + n * 16] = sv[n] * (hx * (float)acc[i][n][rr] + zv[n] * rv);
    }
}

// ---------------- Fallback: fp32 LDS-tiled GEMM reading packed weights (ws too small) ----------------
__global__ __launch_bounds__(256) void fallback_gemm(const float* __restrict__ x,
                                                     const int* __restrict__ pw,
                                                     const float* __restrict__ sc,
                                                     const float* __restrict__ zp,
                                                     float* __restrict__ out) {
  __shared__ float Xs[64][33];
  __shared__ float Ws[64][33];
  const int bid = blockIdx.x;
  const int bm = bid & 63;
  const int bn = bid >> 6;
  const int t = threadIdx.x;
  const int tx = t & 15, ty = t >> 4;
  float acc[4][4] = {};
  for (int k0 = 0; k0 < K_DIM; k0 += 32) {
    __syncthreads();
#pragma unroll
    for (int i = 0; i < 8; ++i) {
      int e = t + i * 256; int rr = e >> 5, c = e & 31;
      Xs[rr][c] = x[(size_t)(bm * 64 + rr) * K_DIM + k0 + c];
    }
#pragma unroll
    for (int i = 0; i < 4; ++i) {
      int e = t + i * 256; int rr = e >> 4, jj = e & 15;
      int row = bn * 64 + rr;
      int v = pw[(size_t)row * KP + (k0 >> 1) + jj];
      float s = sc[row], z = zp[row];
      Ws[rr][2 * jj]     = ((float)(v & 15) - z) * s;
      Ws[rr][2 * jj + 1] = ((float)((v >> 4) & 15) - z) * s;
    }
    __syncthreads();
#pragma unroll
    for (int kk = 0; kk < 32; ++kk) {
      float a[4], b[4];
#pragma unroll
      for (int i2 = 0; i2 < 4; ++i2) a[i2] = Xs[ty * 4 + i2][kk];
#pragma unroll
      for (int j2 = 0; j2 < 4; ++j2) b[j2] = Ws[tx * 4 + j2][kk];
#pragma unroll
      for (int i2 = 0; i2 < 4; ++i2)
#pragma unroll
        for (int j2 = 0; j2 < 4; ++j2) acc[i2][j2] += a[i2] * b[j2];
    }
  }
#pragma unroll
  for (int i2 = 0; i2 < 4; ++i2)
#pragma unroll
    for (int j2 = 0; j2 < 4; ++j2)
      out[(size_t)(bm * 64 + ty * 4 + i2) * N_DIM + bn * 64 + tx * 4 + j2] = acc[i2][j2];
}

extern "C" void kernel_launch(void* const* d_in, const int* in_sizes, int n_in,
                              void* d_out, int out_size, void* d_ws, size_t ws_size,
                              hipStream_t stream) {
  const float* x  = (const float*)d_in[0];
  const int*   pw = (const int*)d_in[1];
  const float* sc = (const float*)d_in[2];
  const float* zp = (const float*)d_in[3];
  float* out = (float*)d_out;

  const size_t wq_b = (size_t)N_DIM * K_DIM;   // 45,088,768
  const size_t xq_b = (size_t)M_DIM * K_DIM;   // 16,777,216
  const size_t need = wq_b + xq_b + 2 * 4096 * sizeof(float);

  if (ws_size >= need) {
    signed char* wq = (signed char*)d_ws;
    signed char* xq = wq + wq_b;
    float* rbuf  = (float*)((char*)d_ws + wq_b + xq_b);
    float* sxbuf = rbuf + 4096;
    hipLaunchKernelGGL(prep,    dim3(4096 + 2048), dim3(256),  0, stream, x, pw, xq, wq, rbuf, sxbuf);
    hipLaunchKernelGGL(gemm_i8, dim3(NWG),         dim3(1024), 0, stream, xq, wq, sc, zp, rbuf, sxbuf, out);
  } else {
    hipLaunchKernelGGL(fallback_gemm, dim3(64 * 172), dim3(256), 0, stream, x, pw, sc, zp, out);
  }
}